// Round 3
// baseline (328.691 us; speedup 1.0000x reference)
//
#include <hip/hip_runtime.h>

// out = min_co( conv2d(x, W, SAME) ) * 2
// x (32,64,128,128) fp32, W (128,64,3,3) fp32 -> out (32,1,128,128) fp32
//
// Round 7: cut the two largest non-MFMA cycle pools found in R6's tally
// (A-read LDS 110k cyc/CU from 4x wave duplication; staging VALU 38k from
// manual bf16 bit-twiddle), keeping the 16-MFMA-per-B-wait cover that R5
// proved necessary.
//   * wave split 2x2x2 (row x pixel-half x co-half): 4 mt x 4 nt frags,
//     A-reads halved (576/block), B L2 traffic 2x (headroom 20x).
//   * v_cvt_pk_bf16_f32 (1 op, RNE) replaces ~8-op manual f2bf pack.
//   * epilogue: nt-min over 4 in-reg, DPP chain on 16 values (was 32),
//     scratch 2 slices (was 4).
//   * keep: conflict-free staging remap, wt[co][tap][ci] imm13 layout,
//     s_setprio around MFMA cluster, DPP row_ror min.

typedef __attribute__((ext_vector_type(8)))  short short8;   // 8 x bf16
typedef __attribute__((ext_vector_type(4)))  float float4v;

#define CI 64
#define CO 128
#define HH 128
#define WW 128
#define WP 130

#define WT_BYTES ((size_t)9 * CO * CI * 2)   // 147,456

__device__ __forceinline__ unsigned short f2bf(float f) {
    unsigned int u = __float_as_uint(f);
    u = (u + 0x7fffu + ((u >> 16) & 1u)) >> 16;   // RNE
    return (unsigned short)u;
}

template <int CTRL>
__device__ __forceinline__ float fminror(float v) {
    int t = __builtin_amdgcn_mov_dpp(__float_as_int(v), CTRL, 0xF, 0xF, false);
    return fminf(v, __int_as_float(t));
}

// ---- prep_w: W (co,ci,3,3) fp32 -> wt[co][tap][ci] bf16 -------------------

__global__ __launch_bounds__(256) void prep_w(
    const float* __restrict__ Wsrc, unsigned short* __restrict__ wt)
{
    int idx = blockIdx.x * 256 + threadIdx.x;          // (tap, co, ci)
    if (idx >= 9 * CO * CI) return;
    int ci  = idx & 63;
    int t   = idx >> 6;
    int co  = t & 127;
    int tap = t >> 7;
    wt[((size_t)co * 9 + tap) * CI + ci] =
        f2bf(Wsrc[((size_t)co * CI + ci) * 9 + tap]);
}

// ---- fused conv + min -----------------------------------------------------

#define LDSA_BYTES (4 * WP * CI * 2)   // 66,560 : 4 padded rows, 128 B/pixel

__global__ __launch_bounds__(512, 4) void conv_fused(
    const float* __restrict__ x,
    const unsigned short* __restrict__ wt,
    float* __restrict__ out)
{
    __shared__ __align__(16) char  ldsA[LDSA_BYTES];
    __shared__ float scratch[2][2][128];

    const int bx   = blockIdx.x;       // output rows 2bx, 2bx+1
    const int b    = blockIdx.y;
    const int tid  = threadIdx.x;
    const int wid  = tid >> 6;
    const int lane = tid & 63;
    const int l15  = lane & 15;
    const int quad = lane >> 4;
    const int hi   = lane >> 5;
    const int wm   = wid & 1;          // output row of the pair
    const int ms   = (wid >> 1) & 1;   // pixel half (64 cols)
    const int wn   = wid >> 2;         // co half (64 co)
    const int n0   = wn * 64;
    const int cb   = ms * 64;          // pixel column base

    // ---- zero pad columns (wp = 0, 129) of all 4 LDS rows ----
    if (tid < 64) {
        int r    = tid >> 4;
        int wp   = ((tid >> 3) & 1) ? 129 : 0;
        int slot = tid & 7;
        float4v z = {0.f, 0.f, 0.f, 0.f};
        *(float4v*)(ldsA + ((size_t)(r * WP + wp) * 128) + slot * 16) = z;
    }
    // ---- zero out-of-bounds rows (edge blocks only; wave-uniform) ----
    if (bx == 0) {                      // LDS row 0 = x row -1
        float4v z = {0.f, 0.f, 0.f, 0.f};
        for (int i = tid; i < WP * CI * 2 / 16; i += 512)
            ((float4v*)ldsA)[i] = z;
    }
    if (bx == HH / 2 - 1) {             // LDS row 3 = x row 128
        float4v z = {0.f, 0.f, 0.f, 0.f};
        for (int i = tid; i < WP * CI * 2 / 16; i += 512)
            ((float4v*)(ldsA + 3 * WP * 128))[i] = z;
    }

    // ---- stage: fp32 -> bf16 transpose into LDS (conflict-free writes) ----
    // Lane remap: ci varies in lane bits 2-4, w-quad in bits 0-1,5 ->
    // each 32-lane phase hits 16 distinct banks (2-way aliased = free).
    {
        const int sm  = wid & 3;                      // staging role
        const int sn  = wid >> 2;
        const int cpl = (lane >> 2) & 7;
        const int qlo = (lane & 3) + 4 * hi;          // 0..7
        const int ci0 = 2 * (cpl + 8 * sm);           // 0..62
        #pragma unroll
        for (int k = 0; k < 8; ++k) {
            const int r = k >> 1;
            const int Q = qlo + 8 * (sn + 2 * (k & 1));   // 0..31
            const int h = 2 * bx - 1 + r;
            if (h >= 0 && h < HH) {
                const float* p0 = x + (((size_t)b * CI + ci0) * HH + h) * WW + Q * 4;
                float4v a0 = *(const float4v*)p0;
                float4v a1 = *(const float4v*)(p0 + (size_t)HH * WW);
                #pragma unroll
                for (int e = 0; e < 4; ++e) {
                    const int wp   = Q * 4 + e + 1;           // 1..128
                    const int slot = (ci0 >> 3) ^ (wp & 7);   // 16B-slot swizzle
                    unsigned int pack;                        // lo=ci0, hi=ci0+1
                    asm("v_cvt_pk_bf16_f32 %0, %1, %2"
                        : "=v"(pack) : "v"(a0[e]), "v"(a1[e]));
                    *(unsigned int*)(ldsA + (size_t)(r * WP + wp) * 128
                                     + slot * 16 + (ci0 & 7) * 2) = pack;
                }
            }
        }
    }
    __syncthreads();

    // ---- K-loop: 9 taps x 2 kc, 16 MFMAs (4mt x 4nt) per B-wait ----
    float4v acc[4][4];
    #pragma unroll
    for (int mt = 0; mt < 4; ++mt)
        #pragma unroll
        for (int nt = 0; nt < 4; ++nt)
            acc[mt][nt] = (float4v){0.f, 0.f, 0.f, 0.f};

    // wt[co][tap][ci]: per-step offset tap*64 + kc*32 elems <= 1088 B (imm13)
    const unsigned short* wb[4];
    #pragma unroll
    for (int nt = 0; nt < 4; ++nt)
        wb[nt] = wt + (size_t)(n0 + nt * 16 + l15) * (9 * CI) + quad * 8;

    short8 bcur[4], bnxt[4];
    #pragma unroll
    for (int nt = 0; nt < 4; ++nt)
        bcur[nt] = *(const short8*)(wb[nt]);

    #pragma unroll
    for (int it = 0; it < 18; ++it) {
        const int tap = it >> 1;
        const int kc  = it & 1;
        const int dh  = tap / 3;
        const int dw  = tap % 3;

        if (it < 17) {                         // prefetch next B fragments
            const int tn  = it + 1;
            const int off = (tn >> 1) * CI + (tn & 1) * 32;
            #pragma unroll
            for (int nt = 0; nt < 4; ++nt)
                bnxt[nt] = *(const short8*)(wb[nt] + off);
        }

        const int key     = (dw + l15) & 7;
        const int rowbase = (wm + dh) * WP + dw + cb + l15;
        const int sp      = ((kc * 4 + quad) ^ key) * 16;

        short8 af[4];
        #pragma unroll
        for (int mt = 0; mt < 4; ++mt)
            af[mt] = *(const short8*)(ldsA + (size_t)(rowbase + mt * 16) * 128 + sp);

        __builtin_amdgcn_s_setprio(1);
        #pragma unroll
        for (int mt = 0; mt < 4; ++mt)
            #pragma unroll
            for (int nt = 0; nt < 4; ++nt)
                acc[mt][nt] = __builtin_amdgcn_mfma_f32_16x16x32_bf16(
                    af[mt], bcur[nt], acc[mt][nt], 0, 0, 0);
        __builtin_amdgcn_s_setprio(0);

        #pragma unroll
        for (int nt = 0; nt < 4; ++nt)
            bcur[nt] = bnxt[nt];
    }

    // ---- epilogue: min over co, *2 ----
    // D: co = n0 + nt*16 + l15, pixel col = cb + mt*16 + quad*4 + reg.
    // 1) fmin across 4 nt in-reg; 2) DPP row_ror min over l15 (VALU, no
    //    LDS); 3) combine the 2 wn slices via scratch.
    float pm[4][4];
    #pragma unroll
    for (int mt = 0; mt < 4; ++mt)
        #pragma unroll
        for (int reg = 0; reg < 4; ++reg)
            pm[mt][reg] = fminf(fminf(acc[mt][0][reg], acc[mt][1][reg]),
                                fminf(acc[mt][2][reg], acc[mt][3][reg]));
    #pragma unroll
    for (int mt = 0; mt < 4; ++mt)
        #pragma unroll
        for (int reg = 0; reg < 4; ++reg) {
            pm[mt][reg] = fminror<0x128>(pm[mt][reg]);   // row_ror:8
            pm[mt][reg] = fminror<0x124>(pm[mt][reg]);   // row_ror:4
            pm[mt][reg] = fminror<0x122>(pm[mt][reg]);   // row_ror:2
            pm[mt][reg] = fminror<0x121>(pm[mt][reg]);   // row_ror:1
        }
    if (l15 == 0) {
        #pragma unroll
        for (int mt = 0; mt < 4; ++mt)
            #pragma unroll
            for (int reg = 0; reg < 4; ++reg)
                scratch[wn][wm][cb + mt * 16 + quad * 4 + reg] = pm[mt][reg];
    }
    __syncthreads();
    if (tid < 256) {
        int r = tid >> 7, c = tid & 127;
        float v = fminf(scratch[0][r][c], scratch[1][r][c]) * 2.0f;
        out[((size_t)b * HH + 2 * bx + r) * WW + c] = v;
    }
}

// ---------------- fallback (round-1 direct conv) ----------------

#define COT 16
__global__ __launch_bounds__(256) void conv_min_fallback(
    const float* __restrict__ x, const float* __restrict__ Wt,
    float* __restrict__ out)
{
    const int b  = blockIdx.y;
    const int h  = blockIdx.x * 2 + (threadIdx.x >> 7);
    const int w  = threadIdx.x & 127;
    const bool r0 = h > 0, r2 = h < HH - 1, c0 = w > 0, c2 = w < WW - 1;
    const float* xb = x + (size_t)b * CI * HH * WW;
    float vmin = 3.4e38f;
    for (int cb = 0; cb < CO; cb += COT) {
        float acc[COT];
        #pragma unroll
        for (int u = 0; u < COT; ++u) acc[u] = 0.0f;
        #pragma unroll 1
        for (int ci = 0; ci < CI; ++ci) {
            const float* xp = xb + ((size_t)ci * HH + h) * WW + w;
            float xv[9];
            xv[0] = (r0 && c0) ? xp[-WW - 1] : 0.0f;
            xv[1] =  r0        ? xp[-WW    ] : 0.0f;
            xv[2] = (r0 && c2) ? xp[-WW + 1] : 0.0f;
            xv[3] =        c0  ? xp[-1     ] : 0.0f;
            xv[4] =              xp[0      ];
            xv[5] =        c2  ? xp[1      ] : 0.0f;
            xv[6] = (r2 && c0) ? xp[ WW - 1] : 0.0f;
            xv[7] =  r2        ? xp[ WW    ] : 0.0f;
            xv[8] = (r2 && c2) ? xp[ WW + 1] : 0.0f;
            #pragma unroll
            for (int u = 0; u < COT; ++u) {
                const float* wp = Wt + ((size_t)(cb + u) * CI + ci) * 9;
                acc[u] += wp[0]*xv[0] + wp[1]*xv[1] + wp[2]*xv[2]
                        + wp[3]*xv[3] + wp[4]*xv[4] + wp[5]*xv[5]
                        + wp[6]*xv[6] + wp[7]*xv[7] + wp[8]*xv[8];
            }
        }
        #pragma unroll
        for (int u = 0; u < COT; ++u) vmin = fminf(vmin, acc[u]);
    }
    out[((size_t)b * HH + h) * WW + w] = vmin * 2.0f;
}

// ---------------- launch ----------------

extern "C" void kernel_launch(void* const* d_in, const int* in_sizes, int n_in,
                              void* d_out, int out_size, void* d_ws, size_t ws_size,
                              hipStream_t stream) {
    const float* x  = (const float*)d_in[0];   // (32,64,128,128)
    const float* Ws = (const float*)d_in[1];   // (128,64,3,3)
    float* out = (float*)d_out;                // (32,1,128,128)

    if (ws_size < WT_BYTES) {
        dim3 grid(HH / 2, 32);
        conv_min_fallback<<<grid, 256, 0, stream>>>(x, Ws, out);
        return;
    }

    unsigned short* wt = (unsigned short*)d_ws;

    prep_w<<<(9 * CO * CI + 255) / 256, 256, 0, stream>>>(Ws, wt);
    conv_fused<<<dim3(HH / 2, 32), 512, 0, stream>>>(x, wt, out);
}

// Round 4
// 308.654 us; speedup vs baseline: 1.0649x; 1.0649x over previous
//
#include <hip/hip_runtime.h>

// out = min_co( conv2d(x, W, SAME) ) * 2
// x (32,64,128,128) fp32, W (128,64,3,3) fp32 -> out (32,1,128,128) fp32
//
// Round 8: R7's 2x2x2 wave split (A-reads halved) was right but spilled
// (WRITE_SIZE 2->113 MB: wb[4] lane pointers + unrolled address temps blew
// the 128-VGPR cap). This round makes addressing register-free:
//   * wt re-laid out [tap][co][ci]: B address = ONE 32-bit lane offset
//     (loff) + uniform compile-time constants (fold to SGPR/imm13, SALU).
//   * A: 6 precomputed LDS bases (dw x kc); dh and mt are ds_read
//     immediates (dh*16640 + mt*2048 < 64 KiB). No per-iter address VALU.
//   Register tally: acc 64 + bcur 16 + bnxt 16 + af 16 + aaddr 6 + misc
//   ~8 = ~126 <= 128. No spill expected.
//   Keep: conflict-free staging remap, v_cvt_pk_bf16_f32, 16-MFMA cover,
//   s_setprio, DPP row_ror epilogue, 2-slice scratch combine.

typedef __attribute__((ext_vector_type(8)))  short short8;   // 8 x bf16
typedef __attribute__((ext_vector_type(4)))  float float4v;

#define CI 64
#define CO 128
#define HH 128
#define WW 128
#define WP 130

#define WT_BYTES ((size_t)9 * CO * CI * 2)   // 147,456

__device__ __forceinline__ unsigned short f2bf(float f) {
    unsigned int u = __float_as_uint(f);
    u = (u + 0x7fffu + ((u >> 16) & 1u)) >> 16;   // RNE
    return (unsigned short)u;
}

template <int CTRL>
__device__ __forceinline__ float fminror(float v) {
    int t = __builtin_amdgcn_mov_dpp(__float_as_int(v), CTRL, 0xF, 0xF, false);
    return fminf(v, __int_as_float(t));
}

// ---- prep_w: W (co,ci,3,3) fp32 -> wt[tap][co][ci] bf16 -------------------

__global__ __launch_bounds__(256) void prep_w(
    const float* __restrict__ Wsrc, unsigned short* __restrict__ wt)
{
    int idx = blockIdx.x * 256 + threadIdx.x;          // (tap, co, ci)
    if (idx >= 9 * CO * CI) return;
    int ci  = idx & 63;
    int t   = idx >> 6;
    int co  = t & 127;
    int tap = t >> 7;
    wt[((size_t)tap * CO + co) * CI + ci] =
        f2bf(Wsrc[((size_t)co * CI + ci) * 9 + tap]);
}

// ---- fused conv + min -----------------------------------------------------

#define LDSA_BYTES (4 * WP * CI * 2)   // 66,560 : 4 padded rows, 128 B/pixel

__global__ __launch_bounds__(512, 4) void conv_fused(
    const float* __restrict__ x,
    const unsigned short* __restrict__ wt,
    float* __restrict__ out)
{
    __shared__ __align__(16) char  ldsA[LDSA_BYTES];
    __shared__ float scratch[2][2][128];

    const int bx   = blockIdx.x;       // output rows 2bx, 2bx+1
    const int b    = blockIdx.y;
    const int tid  = threadIdx.x;
    const int wid  = tid >> 6;
    const int lane = tid & 63;
    const int l15  = lane & 15;
    const int quad = lane >> 4;
    const int hi   = lane >> 5;
    const int wm   = wid & 1;          // output row of the pair
    const int ms   = (wid >> 1) & 1;   // pixel half (64 cols)
    const int wn   = wid >> 2;         // co half (64 co)
    const int n0   = wn * 64;
    const int cb   = ms * 64;          // pixel column base

    // ---- zero pad columns (wp = 0, 129) of all 4 LDS rows ----
    if (tid < 64) {
        int r    = tid >> 4;
        int wp   = ((tid >> 3) & 1) ? 129 : 0;
        int slot = tid & 7;
        float4v z = {0.f, 0.f, 0.f, 0.f};
        *(float4v*)(ldsA + ((size_t)(r * WP + wp) * 128) + slot * 16) = z;
    }
    // ---- zero out-of-bounds rows (edge blocks only; wave-uniform) ----
    if (bx == 0) {                      // LDS row 0 = x row -1
        float4v z = {0.f, 0.f, 0.f, 0.f};
        for (int i = tid; i < WP * CI * 2 / 16; i += 512)
            ((float4v*)ldsA)[i] = z;
    }
    if (bx == HH / 2 - 1) {             // LDS row 3 = x row 128
        float4v z = {0.f, 0.f, 0.f, 0.f};
        for (int i = tid; i < WP * CI * 2 / 16; i += 512)
            ((float4v*)(ldsA + 3 * WP * 128))[i] = z;
    }

    // ---- stage: fp32 -> bf16 transpose into LDS (conflict-free writes) ----
    // Lane remap: ci varies in lane bits 2-4, w-quad in bits 0-1,5 ->
    // each 32-lane phase hits 16 distinct banks (2-way aliased = free).
    {
        const int sm  = wid & 3;                      // staging role
        const int sn  = wid >> 2;
        const int cpl = (lane >> 2) & 7;
        const int qlo = (lane & 3) + 4 * hi;          // 0..7
        const int ci0 = 2 * (cpl + 8 * sm);           // 0..62
        #pragma unroll
        for (int k = 0; k < 8; ++k) {
            const int r = k >> 1;
            const int Q = qlo + 8 * (sn + 2 * (k & 1));   // 0..31
            const int h = 2 * bx - 1 + r;
            if (h >= 0 && h < HH) {
                const float* p0 = x + (((size_t)b * CI + ci0) * HH + h) * WW + Q * 4;
                float4v a0 = *(const float4v*)p0;
                float4v a1 = *(const float4v*)(p0 + (size_t)HH * WW);
                #pragma unroll
                for (int e = 0; e < 4; ++e) {
                    const int wp   = Q * 4 + e + 1;           // 1..128
                    const int slot = (ci0 >> 3) ^ (wp & 7);   // 16B-slot swizzle
                    unsigned int pack;                        // lo=ci0, hi=ci0+1
                    asm("v_cvt_pk_bf16_f32 %0, %1, %2"
                        : "=v"(pack) : "v"(a0[e]), "v"(a1[e]));
                    *(unsigned int*)(ldsA + (size_t)(r * WP + wp) * 128
                                     + slot * 16 + (ci0 & 7) * 2) = pack;
                }
            }
        }
    }
    __syncthreads();

    // ---- K-loop: 9 taps x 2 kc, 16 MFMAs (4mt x 4nt) per B-wait ----
    // A LDS addr: 6 precomputed bases (dw,kc); dh,mt are ds_read imms.
    int aaddr[6];
    #pragma unroll
    for (int dw = 0; dw < 3; ++dw) {
        const int key = (dw + l15) & 7;
        #pragma unroll
        for (int kc = 0; kc < 2; ++kc)
            aaddr[dw * 2 + kc] = (wm * WP + dw + cb + l15) * 128
                               + ((kc * 4 + quad) ^ key) * 16;
    }
    // B: one lane offset; tap/nt/kc are uniform consts (SGPR/imm fold).
    const int loff = (n0 + l15) * CI + quad * 8;

    float4v acc[4][4];
    #pragma unroll
    for (int mt = 0; mt < 4; ++mt)
        #pragma unroll
        for (int nt = 0; nt < 4; ++nt)
            acc[mt][nt] = (float4v){0.f, 0.f, 0.f, 0.f};

    short8 bcur[4], bnxt[4];
    #pragma unroll
    for (int nt = 0; nt < 4; ++nt)
        bcur[nt] = *(const short8*)(wt + loff + nt * 16 * CI);

    #pragma unroll
    for (int it = 0; it < 18; ++it) {
        const int tap = it >> 1;
        const int kc  = it & 1;
        const int dh  = tap / 3;
        const int dw  = tap % 3;

        if (it < 17) {                         // prefetch next B fragments
            const int tn   = it + 1;
            const int tapn = tn >> 1;
            const int kcn  = tn & 1;
            #pragma unroll
            for (int nt = 0; nt < 4; ++nt)
                bnxt[nt] = *(const short8*)(wt + loff
                            + tapn * CO * CI + nt * 16 * CI + kcn * 32);
        }

        const char* ab = ldsA + aaddr[dw * 2 + kc];   // static index
        short8 af[4];
        #pragma unroll
        for (int mt = 0; mt < 4; ++mt)
            af[mt] = *(const short8*)(ab + dh * (WP * 128) + mt * 2048);

        __builtin_amdgcn_s_setprio(1);
        #pragma unroll
        for (int mt = 0; mt < 4; ++mt)
            #pragma unroll
            for (int nt = 0; nt < 4; ++nt)
                acc[mt][nt] = __builtin_amdgcn_mfma_f32_16x16x32_bf16(
                    af[mt], bcur[nt], acc[mt][nt], 0, 0, 0);
        __builtin_amdgcn_s_setprio(0);

        #pragma unroll
        for (int nt = 0; nt < 4; ++nt)
            bcur[nt] = bnxt[nt];
    }

    // ---- epilogue: min over co, *2 ----
    // D: co = n0 + nt*16 + l15, pixel col = cb + mt*16 + quad*4 + reg.
    // 1) fmin across 4 nt in-reg; 2) DPP row_ror min over l15 (VALU, no
    //    LDS); 3) combine the 2 wn slices via scratch.
    float pm[4][4];
    #pragma unroll
    for (int mt = 0; mt < 4; ++mt)
        #pragma unroll
        for (int reg = 0; reg < 4; ++reg)
            pm[mt][reg] = fminf(fminf(acc[mt][0][reg], acc[mt][1][reg]),
                                fminf(acc[mt][2][reg], acc[mt][3][reg]));
    #pragma unroll
    for (int mt = 0; mt < 4; ++mt)
        #pragma unroll
        for (int reg = 0; reg < 4; ++reg) {
            pm[mt][reg] = fminror<0x128>(pm[mt][reg]);   // row_ror:8
            pm[mt][reg] = fminror<0x124>(pm[mt][reg]);   // row_ror:4
            pm[mt][reg] = fminror<0x122>(pm[mt][reg]);   // row_ror:2
            pm[mt][reg] = fminror<0x121>(pm[mt][reg]);   // row_ror:1
        }
    if (l15 == 0) {
        #pragma unroll
        for (int mt = 0; mt < 4; ++mt)
            #pragma unroll
            for (int reg = 0; reg < 4; ++reg)
                scratch[wn][wm][cb + mt * 16 + quad * 4 + reg] = pm[mt][reg];
    }
    __syncthreads();
    if (tid < 256) {
        int r = tid >> 7, c = tid & 127;
        float v = fminf(scratch[0][r][c], scratch[1][r][c]) * 2.0f;
        out[((size_t)b * HH + 2 * bx + r) * WW + c] = v;
    }
}

// ---------------- fallback (round-1 direct conv) ----------------

#define COT 16
__global__ __launch_bounds__(256) void conv_min_fallback(
    const float* __restrict__ x, const float* __restrict__ Wt,
    float* __restrict__ out)
{
    const int b  = blockIdx.y;
    const int h  = blockIdx.x * 2 + (threadIdx.x >> 7);
    const int w  = threadIdx.x & 127;
    const bool r0 = h > 0, r2 = h < HH - 1, c0 = w > 0, c2 = w < WW - 1;
    const float* xb = x + (size_t)b * CI * HH * WW;
    float vmin = 3.4e38f;
    for (int cb = 0; cb < CO; cb += COT) {
        float acc[COT];
        #pragma unroll
        for (int u = 0; u < COT; ++u) acc[u] = 0.0f;
        #pragma unroll 1
        for (int ci = 0; ci < CI; ++ci) {
            const float* xp = xb + ((size_t)ci * HH + h) * WW + w;
            float xv[9];
            xv[0] = (r0 && c0) ? xp[-WW - 1] : 0.0f;
            xv[1] =  r0        ? xp[-WW    ] : 0.0f;
            xv[2] = (r0 && c2) ? xp[-WW + 1] : 0.0f;
            xv[3] =        c0  ? xp[-1     ] : 0.0f;
            xv[4] =              xp[0      ];
            xv[5] =        c2  ? xp[1      ] : 0.0f;
            xv[6] = (r2 && c0) ? xp[ WW - 1] : 0.0f;
            xv[7] =  r2        ? xp[ WW    ] : 0.0f;
            xv[8] = (r2 && c2) ? xp[ WW + 1] : 0.0f;
            #pragma unroll
            for (int u = 0; u < COT; ++u) {
                const float* wp = Wt + ((size_t)(cb + u) * CI + ci) * 9;
                acc[u] += wp[0]*xv[0] + wp[1]*xv[1] + wp[2]*xv[2]
                        + wp[3]*xv[3] + wp[4]*xv[4] + wp[5]*xv[5]
                        + wp[6]*xv[6] + wp[7]*xv[7] + wp[8]*xv[8];
            }
        }
        #pragma unroll
        for (int u = 0; u < COT; ++u) vmin = fminf(vmin, acc[u]);
    }
    out[((size_t)b * HH + h) * WW + w] = vmin * 2.0f;
}

// ---------------- launch ----------------

extern "C" void kernel_launch(void* const* d_in, const int* in_sizes, int n_in,
                              void* d_out, int out_size, void* d_ws, size_t ws_size,
                              hipStream_t stream) {
    const float* x  = (const float*)d_in[0];   // (32,64,128,128)
    const float* Ws = (const float*)d_in[1];   // (128,64,3,3)
    float* out = (float*)d_out;                // (32,1,128,128)

    if (ws_size < WT_BYTES) {
        dim3 grid(HH / 2, 32);
        conv_min_fallback<<<grid, 256, 0, stream>>>(x, Ws, out);
        return;
    }

    unsigned short* wt = (unsigned short*)d_ws;

    prep_w<<<(9 * CO * CI + 255) / 256, 256, 0, stream>>>(Ws, wt);
    conv_fused<<<dim3(HH / 2, 32), 512, 0, stream>>>(x, wt, out);
}

// Round 5
// 299.805 us; speedup vs baseline: 1.0963x; 1.0295x over previous
//
#include <hip/hip_runtime.h>

// out = min_co( conv2d(x, W, SAME) ) * 2
// x (32,64,128,128) fp32, W (128,64,3,3) fp32 -> out (32,1,128,128) fp32
//
// Round 9: break the phase serialization + the register wall.
//   R8 diagnosis: VGPR_Count=64 arch (64 AGPR acc) -> K-loop set (48) +
//   temps spill (WRITE 30 MB); and with 68 KB LDS only 2 blocks/CU, both
//   stage together -> pure-latency phase, then compute phase (BW 1 TB/s,
//   MfmaUtil 17%, nothing saturated).
//   Fix: 1 output row / block, 3 LDS rows = 49.9 KB -> 3 blocks/CU
//   (stage of one block overlaps K-loop of others), 256 thr / 4 waves,
//   wave = 64 px x 64 co -> SAME 16-MFMA cluster (4mt x 4nt).
//   __launch_bounds__(256,3) -> 168 regs/wave = 104 arch + 64 AGPR: the
//   2x2 co/px split finally fits with headroom. No spill.
//   XCD-chunked swizzle: adjacent bx (sharing 2 of 3 input rows) run on
//   the same XCD -> row overlap resolves in L2, fetch stays ~1x.
//   Keep: conflict-free staging remap (R6), v_cvt_pk_bf16_f32,
//   wt[tap][co][ci] imm13 B-addressing (R8), s_setprio, DPP epilogue.

typedef __attribute__((ext_vector_type(8)))  short short8;   // 8 x bf16
typedef __attribute__((ext_vector_type(4)))  float float4v;

#define CI 64
#define CO 128
#define HH 128
#define WW 128
#define WP 130

#define WT_BYTES ((size_t)9 * CO * CI * 2)   // 147,456

__device__ __forceinline__ unsigned short f2bf(float f) {
    unsigned int u = __float_as_uint(f);
    u = (u + 0x7fffu + ((u >> 16) & 1u)) >> 16;   // RNE
    return (unsigned short)u;
}

template <int CTRL>
__device__ __forceinline__ float fminror(float v) {
    int t = __builtin_amdgcn_mov_dpp(__float_as_int(v), CTRL, 0xF, 0xF, false);
    return fminf(v, __int_as_float(t));
}

// ---- prep_w: W (co,ci,3,3) fp32 -> wt[tap][co][ci] bf16 -------------------

__global__ __launch_bounds__(256) void prep_w(
    const float* __restrict__ Wsrc, unsigned short* __restrict__ wt)
{
    int idx = blockIdx.x * 256 + threadIdx.x;          // (tap, co, ci)
    if (idx >= 9 * CO * CI) return;
    int ci  = idx & 63;
    int t   = idx >> 6;
    int co  = t & 127;
    int tap = t >> 7;
    wt[((size_t)tap * CO + co) * CI + ci] =
        f2bf(Wsrc[((size_t)co * CI + ci) * 9 + tap]);
}

// ---- fused conv + min -----------------------------------------------------

#define LDSA_BYTES (3 * WP * CI * 2)   // 49,920 : 3 padded rows, 128 B/pixel

__global__ __launch_bounds__(256, 3) void conv_fused(
    const float* __restrict__ x,
    const unsigned short* __restrict__ wt,
    float* __restrict__ out)
{
    __shared__ __align__(16) char  ldsA[LDSA_BYTES];
    __shared__ float scratch[2][128];

    // XCD-chunked decode: 4096 blocks; xcd = slot%8 gets bx band
    // [16*xcd, 16*xcd+16) for all batches -> adjacent-bx row reuse in L2.
    const int gid = blockIdx.x;            // 0..4095
    const int xcd = gid & 7;
    const int j   = gid >> 3;
    const int bx  = xcd * 16 + (j & 15);   // output row 0..127
    const int b   = j >> 4;                // batch 0..31

    const int tid  = threadIdx.x;
    const int wid  = tid >> 6;
    const int lane = tid & 63;
    const int l15  = lane & 15;
    const int quad = lane >> 4;
    const int hi   = lane >> 5;
    const int ms   = wid & 1;          // pixel half (64 cols)
    const int wn   = wid >> 1;         // co half (64 co)
    const int n0   = wn * 64;
    const int cb   = ms * 64;          // pixel column base

    // ---- zero pad columns (wp = 0, 129) of all 3 LDS rows ----
    if (tid < 48) {
        int r    = tid >> 4;                       // 0..2
        int wp   = ((tid >> 3) & 1) ? 129 : 0;
        int slot = tid & 7;
        float4v z = {0.f, 0.f, 0.f, 0.f};
        *(float4v*)(ldsA + ((size_t)(r * WP + wp) * 128) + slot * 16) = z;
    }
    // ---- zero out-of-bounds rows (edge blocks only; uniform branch) ----
    if (bx == 0) {                      // LDS row 0 = x row -1
        float4v z = {0.f, 0.f, 0.f, 0.f};
        for (int i = tid; i < WP * CI * 2 / 16; i += 256)
            ((float4v*)ldsA)[i] = z;
    }
    if (bx == HH - 1) {                 // LDS row 2 = x row 128
        float4v z = {0.f, 0.f, 0.f, 0.f};
        for (int i = tid; i < WP * CI * 2 / 16; i += 256)
            ((float4v*)(ldsA + 2 * WP * 128))[i] = z;
    }

    // ---- B setup early (loads overlap staging latency) ----
    // wt[tap][co][ci]: one 32-bit lane offset; tap/nt/kc are uniform
    // compile-time constants (fold to SGPR base + imm13).
    const int loff = (n0 + l15) * CI + quad * 8;
    short8 bcur[4], bnxt[4];
    #pragma unroll
    for (int nt = 0; nt < 4; ++nt)
        bcur[nt] = *(const short8*)(wt + loff + nt * 16 * CI);

    // ---- stage: fp32 -> bf16 transpose into LDS (conflict-free writes) ----
    // ci varies in lane bits 2-4, w-quad in bits 0-1,5 + wid: each 32-lane
    // phase hits 16 distinct banks (2-way aliased = free).
    {
        const int cpl = (lane >> 2) & 7;
        const int qlo = (lane & 3) + 4 * hi;      // 0..7
        const int Q   = qlo + 8 * wid;            // 0..31
        #pragma unroll 1
        for (int r = 0; r < 3; ++r) {
            const int h = bx - 1 + r;
            if (h >= 0 && h < HH) {
                #pragma unroll
                for (int u = 0; u < 4; ++u) {
                    const int ci0 = 2 * (cpl + 8 * u);    // 0..62
                    const float* p0 = x + (((size_t)b * CI + ci0) * HH + h) * WW + Q * 4;
                    float4v a0 = *(const float4v*)p0;
                    float4v a1 = *(const float4v*)(p0 + (size_t)HH * WW);
                    #pragma unroll
                    for (int e = 0; e < 4; ++e) {
                        const int wp   = Q * 4 + e + 1;           // 1..128
                        const int slot = (ci0 >> 3) ^ (wp & 7);   // 16B-slot swizzle
                        unsigned int pack;                        // lo=ci0, hi=ci0+1
                        asm("v_cvt_pk_bf16_f32 %0, %1, %2"
                            : "=v"(pack) : "v"(a0[e]), "v"(a1[e]));
                        *(unsigned int*)(ldsA + (size_t)(r * WP + wp) * 128
                                         + slot * 16 + (ci0 & 7) * 2) = pack;
                    }
                }
            }
        }
    }
    __syncthreads();

    // ---- K-loop: 9 taps x 2 kc, 16 MFMAs (4mt x 4nt) per B-wait ----
    // A addr: 6 bases (dw,kc); dh,mt are ds_read imms (max 39424 < 64K).
    int aaddr[6];
    #pragma unroll
    for (int dw = 0; dw < 3; ++dw) {
        const int key = (dw + l15) & 7;
        #pragma unroll
        for (int kc = 0; kc < 2; ++kc)
            aaddr[dw * 2 + kc] = (dw + cb + l15) * 128
                               + (((kc * 4 + quad) ^ key)) * 16;
    }

    float4v acc[4][4];
    #pragma unroll
    for (int mt = 0; mt < 4; ++mt)
        #pragma unroll
        for (int nt = 0; nt < 4; ++nt)
            acc[mt][nt] = (float4v){0.f, 0.f, 0.f, 0.f};

    #pragma unroll
    for (int it = 0; it < 18; ++it) {
        const int tap = it >> 1;
        const int kc  = it & 1;
        const int dh  = tap / 3;
        const int dw  = tap % 3;

        if (it < 17) {                         // prefetch next B fragments
            const int tn   = it + 1;
            const int tapn = tn >> 1;
            const int kcn  = tn & 1;
            #pragma unroll
            for (int nt = 0; nt < 4; ++nt)
                bnxt[nt] = *(const short8*)(wt + loff
                            + tapn * CO * CI + nt * 16 * CI + kcn * 32);
        }

        const char* ab = ldsA + aaddr[dw * 2 + kc];   // static index
        short8 af[4];
        #pragma unroll
        for (int mt = 0; mt < 4; ++mt)
            af[mt] = *(const short8*)(ab + dh * (WP * 128) + mt * 2048);

        __builtin_amdgcn_s_setprio(1);
        #pragma unroll
        for (int mt = 0; mt < 4; ++mt)
            #pragma unroll
            for (int nt = 0; nt < 4; ++nt)
                acc[mt][nt] = __builtin_amdgcn_mfma_f32_16x16x32_bf16(
                    af[mt], bcur[nt], acc[mt][nt], 0, 0, 0);
        __builtin_amdgcn_s_setprio(0);

        #pragma unroll
        for (int nt = 0; nt < 4; ++nt)
            bcur[nt] = bnxt[nt];
    }

    // ---- epilogue: min over co, *2 ----
    // D: co = n0 + nt*16 + l15, pixel col = cb + mt*16 + quad*4 + reg.
    float pm[4][4];
    #pragma unroll
    for (int mt = 0; mt < 4; ++mt)
        #pragma unroll
        for (int reg = 0; reg < 4; ++reg)
            pm[mt][reg] = fminf(fminf(acc[mt][0][reg], acc[mt][1][reg]),
                                fminf(acc[mt][2][reg], acc[mt][3][reg]));
    #pragma unroll
    for (int mt = 0; mt < 4; ++mt)
        #pragma unroll
        for (int reg = 0; reg < 4; ++reg) {
            pm[mt][reg] = fminror<0x128>(pm[mt][reg]);   // row_ror:8
            pm[mt][reg] = fminror<0x124>(pm[mt][reg]);   // row_ror:4
            pm[mt][reg] = fminror<0x122>(pm[mt][reg]);   // row_ror:2
            pm[mt][reg] = fminror<0x121>(pm[mt][reg]);   // row_ror:1
        }
    if (l15 == 0) {
        #pragma unroll
        for (int mt = 0; mt < 4; ++mt)
            #pragma unroll
            for (int reg = 0; reg < 4; ++reg)
                scratch[wn][cb + mt * 16 + quad * 4 + reg] = pm[mt][reg];
    }
    __syncthreads();
    if (tid < 128) {
        float v = fminf(scratch[0][tid], scratch[1][tid]) * 2.0f;
        out[((size_t)b * HH + bx) * WW + tid] = v;
    }
}

// ---------------- fallback (round-1 direct conv) ----------------

#define COT 16
__global__ __launch_bounds__(256) void conv_min_fallback(
    const float* __restrict__ x, const float* __restrict__ Wt,
    float* __restrict__ out)
{
    const int b  = blockIdx.y;
    const int h  = blockIdx.x * 2 + (threadIdx.x >> 7);
    const int w  = threadIdx.x & 127;
    const bool r0 = h > 0, r2 = h < HH - 1, c0 = w > 0, c2 = w < WW - 1;
    const float* xb = x + (size_t)b * CI * HH * WW;
    float vmin = 3.4e38f;
    for (int cb = 0; cb < CO; cb += COT) {
        float acc[COT];
        #pragma unroll
        for (int u = 0; u < COT; ++u) acc[u] = 0.0f;
        #pragma unroll 1
        for (int ci = 0; ci < CI; ++ci) {
            const float* xp = xb + ((size_t)ci * HH + h) * WW + w;
            float xv[9];
            xv[0] = (r0 && c0) ? xp[-WW - 1] : 0.0f;
            xv[1] =  r0        ? xp[-WW    ] : 0.0f;
            xv[2] = (r0 && c2) ? xp[-WW + 1] : 0.0f;
            xv[3] =        c0  ? xp[-1     ] : 0.0f;
            xv[4] =              xp[0      ];
            xv[5] =        c2  ? xp[1      ] : 0.0f;
            xv[6] = (r2 && c0) ? xp[ WW - 1] : 0.0f;
            xv[7] =  r2        ? xp[ WW    ] : 0.0f;
            xv[8] = (r2 && c2) ? xp[ WW + 1] : 0.0f;
            #pragma unroll
            for (int u = 0; u < COT; ++u) {
                const float* wp = Wt + ((size_t)(cb + u) * CI + ci) * 9;
                acc[u] += wp[0]*xv[0] + wp[1]*xv[1] + wp[2]*xv[2]
                        + wp[3]*xv[3] + wp[4]*xv[4] + wp[5]*xv[5]
                        + wp[6]*xv[6] + wp[7]*xv[7] + wp[8]*xv[8];
            }
        }
        #pragma unroll
        for (int u = 0; u < COT; ++u) vmin = fminf(vmin, acc[u]);
    }
    out[((size_t)b * HH + h) * WW + w] = vmin * 2.0f;
}

// ---------------- launch ----------------

extern "C" void kernel_launch(void* const* d_in, const int* in_sizes, int n_in,
                              void* d_out, int out_size, void* d_ws, size_t ws_size,
                              hipStream_t stream) {
    const float* x  = (const float*)d_in[0];   // (32,64,128,128)
    const float* Ws = (const float*)d_in[1];   // (128,64,3,3)
    float* out = (float*)d_out;                // (32,1,128,128)

    if (ws_size < WT_BYTES) {
        dim3 grid(HH / 2, 32);
        conv_min_fallback<<<grid, 256, 0, stream>>>(x, Ws, out);
        return;
    }

    unsigned short* wt = (unsigned short*)d_ws;

    prep_w<<<(9 * CO * CI + 255) / 256, 256, 0, stream>>>(Ws, wt);
    conv_fused<<<4096, 256, 0, stream>>>(x, wt, out);
}